// Round 1
// baseline (851.724 us; speedup 1.0000x reference)
//
#include <hip/hip_runtime.h>

// CostVolume: B=4,H=256,W=512,C=64,D=64 (all fixed by setup_inputs).
// out[b,h,w,d] = (w-d-1>=0) ? (1/64) * sum_c L[b,h,w,c]*R[b,h,w-d-1,c] : 0
//
// Band-matmul in (w, w'=w-d-1) space. Register-resident sliding window of R:
// each lane of a wave holds one full R row (64 fp32 = 16 float4 in VGPRs),
// mapped by lane = row mod 64. Per w-step exactly one lane reloads one
// contiguous 256B row; L[w,:] is wave-uniform broadcast; each lane emits one
// output scalar, and the wave's 64 stores cover out[b,h,w,0..63] contiguously
// (d = w-1-row is a rotation of 0..63 across lanes). No LDS.

#define WW 512
#define CC 64
#define DMAX 64
#define TW 128   // w-steps per wave; 4 waves/block cover the full W=512 row

__global__ __launch_bounds__(256, 4)
void CostVolume_47433618817551_kernel(const float* __restrict__ left,
                                      const float* __restrict__ right,
                                      float* __restrict__ out) {
    const int lane = threadIdx.x & 63;
    const int wave = threadIdx.x >> 6;
    const int bh   = blockIdx.x;                 // 0..B*H-1 = 0..1023

    const float* L = left  + (size_t)bh * (WW * CC);
    const float* R = right + (size_t)bh * (WW * CC);
    float*       O = out   + (size_t)bh * (WW * DMAX);

    const int w0 = wave * TW;

    // Per-lane register copy of one R row (sliding window [w-64, w-1]).
    float4 r[16];
#pragma unroll
    for (int i = 0; i < 16; ++i) r[i] = make_float4(0.f, 0.f, 0.f, 0.f);

    // Initial window rows: [w0-64, w0-1]; lane l holds row w0-64+l
    // (w0 is a multiple of 64, so row mod 64 == lane).
    int rrow = w0 - 64 + lane;
    if (rrow >= 0) {
        const float4* rp = (const float4*)(R + (size_t)rrow * CC);
#pragma unroll
        for (int i = 0; i < 16; ++i) r[i] = rp[i];
    }

    for (int w = w0; w < w0 + TW; ++w) {
        // Slide window: lane holding row w-65 (lane == (w-1)&63) takes row w-1.
        if (w > w0 && lane == ((w - 1) & 63)) {
            rrow = w - 1;
            const float4* rp = (const float4*)(R + (size_t)rrow * CC);
#pragma unroll
            for (int i = 0; i < 16; ++i) r[i] = rp[i];
        }

        // L[w,:] is wave-uniform -> broadcast loads (one segment per inst).
        const float4* lp = (const float4*)(L + (size_t)w * CC);
        float a0 = 0.f, a1 = 0.f, a2 = 0.f, a3 = 0.f;
#pragma unroll
        for (int i = 0; i < 16; ++i) {
            const float4 lv = lp[i];
            a0 += lv.x * r[i].x;
            a1 += lv.y * r[i].y;
            a2 += lv.z * r[i].z;
            a3 += lv.w * r[i].w;
        }
        const float acc = (a0 + a1) + (a2 + a3);

        const int d = w - 1 - rrow;              // rotation of 0..63 across lanes
        const float val = (rrow >= 0) ? acc * (1.0f / 64.0f) : 0.0f;
        O[(size_t)w * DMAX + d] = val;
    }
}

extern "C" void kernel_launch(void* const* d_in, const int* in_sizes, int n_in,
                              void* d_out, int out_size, void* d_ws, size_t ws_size,
                              hipStream_t stream) {
    const float* left  = (const float*)d_in[0];
    const float* right = (const float*)d_in[1];
    float* out = (float*)d_out;

    // B*H = 1024 blocks; 4 waves/block each covering TW=128 w-steps.
    CostVolume_47433618817551_kernel<<<dim3(1024), dim3(256), 0, stream>>>(
        left, right, out);
}

// Round 2
// 618.084 us; speedup vs baseline: 1.3780x; 1.3780x over previous
//
#include <hip/hip_runtime.h>

// CostVolume: B=4,H=256,W=512,C=64,D=64.
// out[b,h,w,d] = (w-d-1>=0) ? (1/64) * sum_c L[b,h,w,c]*R[b,h,w-d-1,c] : 0
//
// Register-resident sliding window of R: each lane of a wave holds one full
// R row (64 fp32) in 16 NAMED float4 registers (named scalars, not an array,
// so SROA keeps them in VGPRs — round 1's array form spilled: VGPR_Count=52
// < the 64 needed, 670us). Window maps row -> lane via lane = row mod 64;
// per w-step exactly one lane reloads one contiguous 256B row.
// L[w,:] is wave-uniform: `wave` is laundered through readfirstlane so the
// compiler can prove uniformity and emit s_load -> L lives in SGPRs, costing
// zero VGPRs; FMAs are v_fma_f32 v,s,v (1 sgpr read per VALU inst is legal).
// The wave's 64 output scalars per step cover out[b,h,w,0..63] contiguously
// (d = w-1-rrow is a rotation of 0..63 across lanes). No LDS.

#define WW 512
#define CC 64
#define DMAX 64
#define TW 128   // w-steps per wave; 4 waves/block cover W=512

#define R16(F) F(0) F(1) F(2) F(3) F(4) F(5) F(6) F(7) \
               F(8) F(9) F(10) F(11) F(12) F(13) F(14) F(15)

__global__ __launch_bounds__(256, 2)
void CostVolume_47433618817551_kernel(const float* __restrict__ left,
                                      const float* __restrict__ right,
                                      float* __restrict__ out) {
    const int lane = threadIdx.x & 63;
    // Launder wave index so uniformity analysis sees L-row addresses as
    // wave-uniform -> scalar loads.
    const int wave = __builtin_amdgcn_readfirstlane((int)(threadIdx.x >> 6));
    const int bh   = blockIdx.x;                 // 0..B*H-1

    const float* L = left  + (size_t)bh * (WW * CC);
    const float* R = right + (size_t)bh * (WW * CC);
    float*       O = out   + (size_t)bh * (WW * DMAX);

    const int w0 = wave * TW;

    // Sliding window of R rows, one row per lane, in named registers.
#define DECL(i) float4 r##i = make_float4(0.f, 0.f, 0.f, 0.f);
    R16(DECL)
#undef DECL

#define RELOAD(i) r##i = rp[i];

    // Initial window rows [w0-64, w0-1]; lane l holds row w0-64+l
    // (w0 % 64 == 0, so row % 64 == lane).
    int rrow = w0 - 64 + lane;
    if (rrow >= 0) {
        const float4* rp = (const float4*)(R + (size_t)rrow * CC);
        R16(RELOAD)
    }

    for (int w = w0; w < w0 + TW; ++w) {
        // Slide: lane (w-1)&63 replaces its row (w-65) with row w-1.
        if (w > w0 && lane == ((w - 1) & 63)) {
            rrow = w - 1;
            const float4* rp = (const float4*)(R + (size_t)rrow * CC);
            R16(RELOAD)
        }

        // Wave-uniform L row -> s_load into SGPRs.
        const float* lp = L + (size_t)w * CC;
        float a0 = 0.f, a1 = 0.f, a2 = 0.f, a3 = 0.f;
#define FMA(i) { a0 = fmaf(lp[4*(i)+0], r##i.x, a0); \
                 a1 = fmaf(lp[4*(i)+1], r##i.y, a1); \
                 a2 = fmaf(lp[4*(i)+2], r##i.z, a2); \
                 a3 = fmaf(lp[4*(i)+3], r##i.w, a3); }
        R16(FMA)
#undef FMA

        const float val = (rrow >= 0) ? ((a0 + a1) + (a2 + a3)) * 0.015625f
                                      : 0.0f;
        O[(size_t)w * DMAX + (w - 1 - rrow)] = val;   // d = w-1-rrow
    }
#undef RELOAD
}

extern "C" void kernel_launch(void* const* d_in, const int* in_sizes, int n_in,
                              void* d_out, int out_size, void* d_ws, size_t ws_size,
                              hipStream_t stream) {
    const float* left  = (const float*)d_in[0];
    const float* right = (const float*)d_in[1];
    float* out = (float*)d_out;

    // B*H = 1024 blocks; 4 waves/block, each covering TW=128 w-steps.
    CostVolume_47433618817551_kernel<<<dim3(1024), dim3(256), 0, stream>>>(
        left, right, out);
}

// Round 3
// 592.264 us; speedup vs baseline: 1.4381x; 1.0436x over previous
//
#include <hip/hip_runtime.h>

// CostVolume: B=4,H=256,W=512,C=64,D=64.
// out[b,h,w,d] = (w-d-1>=0) ? (1/64) * sum_c L[b,h,w,c]*R[b,h,w-d-1,c] : 0
//
// Register-resident sliding window of R: each lane holds one full R row
// (64 fp32 = 16 x 128-bit VGPR quads), row -> lane via lane = row mod 64.
// Per w-step one lane reloads one contiguous 256B row. L[w,:] is wave-uniform
// (laundered via readfirstlane) -> s_load into SGPRs (R2: SGPR_Count=96
// confirmed). R2 failure mode: compiler REMATERIALIZED the window (VGPR=40,
// re-loading R from global every step -> latency-bound, 428us). Fix: empty
// asm volatile with "+v" on all 16 quads each iteration makes the values
// opaque asm outputs -> non-rematerializable, must stay in VGPRs.

#define WW 512
#define CC 64
#define DMAX 64
#define TW 128   // w-steps per wave; 4 waves/block cover W=512

typedef float v4 __attribute__((ext_vector_type(4)));

#define R16(F) F(0) F(1) F(2) F(3) F(4) F(5) F(6) F(7) \
               F(8) F(9) F(10) F(11) F(12) F(13) F(14) F(15)

__global__ __launch_bounds__(256, 4)
void CostVolume_47433618817551_kernel(const float* __restrict__ left,
                                      const float* __restrict__ right,
                                      float* __restrict__ out) {
    const int lane = threadIdx.x & 63;
    const int wave = __builtin_amdgcn_readfirstlane((int)(threadIdx.x >> 6));
    const int bh   = blockIdx.x;                 // 0..B*H-1

    const float* L = left  + (size_t)bh * (WW * CC);
    const float* R = right + (size_t)bh * (WW * CC);
    float*       O = out   + (size_t)bh * (WW * DMAX);

    const int w0 = wave * TW;

    // Sliding window of R rows, one row per lane, in 16 named 128-bit regs.
#define DECL(i) v4 r##i = {0.f, 0.f, 0.f, 0.f};
    R16(DECL)
#undef DECL

#define RELOAD(i) r##i = rp[i];

    // Initial window rows [w0-64, w0-1]; lane l holds row w0-64+l
    // (w0 % 64 == 0, so row % 64 == lane).
    int rrow = w0 - 64 + lane;
    if (rrow >= 0) {
        const v4* rp = (const v4*)(R + (size_t)rrow * CC);
        R16(RELOAD)
    }

    for (int w = w0; w < w0 + TW; ++w) {
        // Slide: lane (w-1)&63 replaces its row (w-65) with row w-1.
        if (w > w0 && lane == ((w - 1) & 63)) {
            rrow = w - 1;
            const v4* rp = (const v4*)(R + (size_t)rrow * CC);
            R16(RELOAD)
        }

        // Pin the window in VGPRs: opaque asm def kills rematerialization.
        asm volatile("" : "+v"(r0), "+v"(r1), "+v"(r2),  "+v"(r3),
                          "+v"(r4), "+v"(r5), "+v"(r6),  "+v"(r7),
                          "+v"(r8), "+v"(r9), "+v"(r10), "+v"(r11),
                          "+v"(r12),"+v"(r13),"+v"(r14), "+v"(r15));

        // Wave-uniform L row -> s_load into SGPRs; v_fma v,s,v is legal
        // (1 SGPR read per VALU inst).
        const v4* lp = (const v4*)(L + (size_t)w * CC);
        v4 acc = {0.f, 0.f, 0.f, 0.f};
#define FMA(i) acc += lp[i] * r##i;
        R16(FMA)
#undef FMA

        const float s = (acc.x + acc.y) + (acc.z + acc.w);
        const float val = (rrow >= 0) ? s * 0.015625f : 0.0f;
        O[(size_t)w * DMAX + (w - 1 - rrow)] = val;   // d = w-1-rrow
    }
#undef RELOAD
}

extern "C" void kernel_launch(void* const* d_in, const int* in_sizes, int n_in,
                              void* d_out, int out_size, void* d_ws, size_t ws_size,
                              hipStream_t stream) {
    const float* left  = (const float*)d_in[0];
    const float* right = (const float*)d_in[1];
    float* out = (float*)d_out;

    // B*H = 1024 blocks; 4 waves/block, each covering TW=128 w-steps.
    CostVolume_47433618817551_kernel<<<dim3(1024), dim3(256), 0, stream>>>(
        left, right, out);
}